// Round 5
// baseline (514.182 us; speedup 1.0000x reference)
//
#include <hip/hip_runtime.h>
#include <hip/hip_bf16.h>
#include <math.h>

// Problem constants
#define HD 1024     // hidden H
#define ID 512      // moe intermediate I
#define NE 32       // n experts
#define NT 2048     // tokens T = B*S
#define NG 4        // n_group
#define SHI 1024    // shared intermediate I*N_SHARED
#define SCALE 2.5f

#define BK 32
#define LDA 40      // LDS row stride in bf16 (32 + 8 pad -> 80B rows)

typedef __bf16 bf16_t;
typedef __attribute__((ext_vector_type(8))) __bf16 bf16x8;
typedef __attribute__((ext_vector_type(4))) __bf16 bf16x4;
typedef __attribute__((ext_vector_type(4))) float f32x4;

// ---------------- router stage 1: logits GEMM + zero counts ----------------
#define LTOK 8
#define LKC 64
__global__ void __launch_bounds__(256) logits_kernel(
    const float* __restrict__ hs, const float* __restrict__ rw,
    float* __restrict__ logits, int* __restrict__ counts)
{
    if (blockIdx.x == 0 && threadIdx.x < NE) counts[threadIdx.x] = 0;

    __shared__ float Xs[LTOK][68];
    __shared__ float Ws[NE][65];

    int tid = threadIdx.x;
    int t0 = blockIdx.x * LTOK;
    int tslot = tid >> 5, ecol = tid & 31;
    float acc = 0.f;

    for (int k0 = 0; k0 < HD; k0 += LKC) {
        if (tid < 128) {
            int row = tid >> 4, q = tid & 15;
            float4 v = *(const float4*)(hs + (size_t)(t0 + row) * HD + k0 + q * 4);
            *(float4*)(&Xs[row][q * 4]) = v;
        }
        #pragma unroll
        for (int i = 0; i < 8; ++i) {
            int idx = i * 256 + tid;
            int e = idx >> 6, kk = idx & 63;
            Ws[e][kk] = rw[(size_t)e * HD + k0 + kk];
        }
        __syncthreads();
        #pragma unroll 8
        for (int kk = 0; kk < LKC; ++kk)
            acc += Xs[tslot][kk] * Ws[ecol][kk];
        __syncthreads();
    }
    logits[(size_t)(t0 + tslot) * NE + ecol] = acc;
}

// ---------------- router stage 2: per-token top-k ----------------
__global__ void __launch_bounds__(256) topk_kernel(
    const float* __restrict__ logits, const float* __restrict__ rb,
    float* __restrict__ topkw, int* __restrict__ counts, int* __restrict__ lists)
{
    int t = blockIdx.x * 256 + threadIdx.x;
    if (t >= NT) return;

    float scores[NE], sfc[NE], tmp[NE];
    #pragma unroll
    for (int e = 0; e < NE; ++e) {
        float l = logits[(size_t)t * NE + e];
        float s = 1.f / (1.f + __expf(-l));
        scores[e] = s;
        sfc[e] = s + rb[e];
    }
    float gs[NG];
    #pragma unroll
    for (int g = 0; g < NG; ++g) {
        float m1 = -1e30f, m2 = -1e30f;
        #pragma unroll
        for (int j = 0; j < 8; ++j) {
            float v = sfc[g * 8 + j];
            if (v > m1) { m2 = m1; m1 = v; } else if (v > m2) m2 = v;
        }
        gs[g] = m1 + m2;
    }
    int g1 = 0;
    #pragma unroll
    for (int g = 1; g < NG; ++g) if (gs[g] > gs[g1]) g1 = g;
    int g2 = -1;
    #pragma unroll
    for (int g = 0; g < NG; ++g) {
        if (g == g1) continue;
        if (g2 < 0 || gs[g] > gs[g2]) g2 = g;
    }
    #pragma unroll
    for (int e = 0; e < NE; ++e) {
        int g = e >> 3;
        tmp[e] = (g == g1 || g == g2) ? sfc[e] : 0.0f;
    }
    int idx[4]; float wk[4]; float wsum = 0.f;
    #pragma unroll
    for (int k = 0; k < 4; ++k) {
        int best = 0; float bv = -1e30f;
        #pragma unroll
        for (int e = 0; e < NE; ++e) if (tmp[e] > bv) { bv = tmp[e]; best = e; }
        idx[k] = best; tmp[best] = -1e30f;
        wk[k] = scores[best]; wsum += wk[k];
    }
    float inv = SCALE / (wsum + 1e-20f);
    #pragma unroll
    for (int k = 0; k < 4; ++k) {
        int p = t * 4 + k;
        topkw[p] = wk[k] * inv;
        int e = idx[k];
        int pos = atomicAdd(&counts[e], 1);
        lists[e * NT + pos] = p;
    }
}

__device__ inline bf16x4 cvt4(float4 v) {
    bf16x4 r;
    r[0] = (__bf16)v.x; r[1] = (__bf16)v.y; r[2] = (__bf16)v.z; r[3] = (__bf16)v.w;
    return r;
}

// ---------------- fused gate/up + SwiGLU, bf16 MFMA, small tiles for TLP ----------------
// X fp32 [tokens, HD]; Wg/Wu fp32 [(E,) ND, HD]; Hout bf16 [rows, ND]
// 4 waves arranged 2x2; wave tile = (BMT/2) x (BNT/2).
template<bool EXPERT, int ND, int BMT, int BNT>
__global__ void __launch_bounds__(256) gateup_mfma(
    const float* __restrict__ X, const float* __restrict__ Wg,
    const float* __restrict__ Wu, bf16_t* __restrict__ Hout,
    const int* __restrict__ lists, const int* __restrict__ counts)
{
    int e = 0, cnt = NT;
    const float* wg = Wg; const float* wu = Wu;
    if (EXPERT) {
        e = blockIdx.x; cnt = counts[e];
        wg = Wg + (size_t)e * ND * HD;
        wu = Wu + (size_t)e * ND * HD;
    }
    int mtb = blockIdx.y, ntb = blockIdx.z;
    if (mtb * BMT >= cnt) return;

    constexpr int RM = BMT / 2;           // rows per wave
    constexpr int RN = BNT / 2;           // cols per wave
    constexpr int MT = RM / 16;           // 16-row m-tiles per wave
    constexpr int NTt = RN / 16;          // 16-col n-tiles per wave
    constexpr int AR = (BMT * BK) / (256 * 4);  // float4/thread for A
    constexpr int BR = (BNT * BK) / (256 * 4);  // float4/thread per B tensor

    __shared__ __align__(16) bf16_t As[BMT * LDA];
    __shared__ __align__(16) bf16_t Bgs[BNT * LDA];
    __shared__ __align__(16) bf16_t Bus[BNT * LDA];
    __shared__ int rowid[BMT];

    int tid = threadIdx.x;
    if (tid < BMT) {
        int gm = mtb * BMT + tid;
        int mm = gm < cnt ? gm : cnt - 1;
        rowid[tid] = EXPERT ? lists[e * NT + mm] : mm;
    }
    __syncthreads();

    int lane = tid & 63;
    int w = tid >> 6;
    int wm = w & 1, wn = w >> 1;
    int lrow = lane & 15, quad = lane >> 4;

    f32x4 accg[MT][NTt], accu[MT][NTt];
    #pragma unroll
    for (int i = 0; i < MT; ++i)
        #pragma unroll
        for (int j = 0; j < NTt; ++j) { accg[i][j] = (f32x4){0,0,0,0}; accu[i][j] = (f32x4){0,0,0,0}; }

    for (int k0 = 0; k0 < HD; k0 += BK) {
        #pragma unroll
        for (int r = 0; r < AR; ++r) {
            int idx = r * 256 + tid;
            int row = idx >> 3, kq = idx & 7;
            int tok = EXPERT ? (rowid[row] >> 2) : rowid[row];
            float4 v = *(const float4*)(X + (size_t)tok * HD + k0 + kq * 4);
            *(bf16x4*)(As + row * LDA + kq * 4) = cvt4(v);
        }
        #pragma unroll
        for (int r = 0; r < BR; ++r) {
            int idx = r * 256 + tid;
            int n = idx >> 3, kq = idx & 7;
            size_t off = (size_t)(ntb * BNT + n) * HD + k0 + kq * 4;
            *(bf16x4*)(Bgs + n * LDA + kq * 4) = cvt4(*(const float4*)(wg + off));
            *(bf16x4*)(Bus + n * LDA + kq * 4) = cvt4(*(const float4*)(wu + off));
        }
        __syncthreads();

        bf16x8 af[MT], bg[NTt], bu[NTt];
        #pragma unroll
        for (int mt = 0; mt < MT; ++mt)
            af[mt] = *(const bf16x8*)(As + (wm * RM + mt * 16 + lrow) * LDA + quad * 8);
        #pragma unroll
        for (int nt = 0; nt < NTt; ++nt) {
            bg[nt] = *(const bf16x8*)(Bgs + (wn * RN + nt * 16 + lrow) * LDA + quad * 8);
            bu[nt] = *(const bf16x8*)(Bus + (wn * RN + nt * 16 + lrow) * LDA + quad * 8);
        }
        #pragma unroll
        for (int mt = 0; mt < MT; ++mt)
            #pragma unroll
            for (int nt = 0; nt < NTt; ++nt) {
                accg[mt][nt] = __builtin_amdgcn_mfma_f32_16x16x32_bf16(af[mt], bg[nt], accg[mt][nt], 0, 0, 0);
                accu[mt][nt] = __builtin_amdgcn_mfma_f32_16x16x32_bf16(af[mt], bu[nt], accu[mt][nt], 0, 0, 0);
            }
        __syncthreads();
    }

    #pragma unroll
    for (int mt = 0; mt < MT; ++mt)
        #pragma unroll
        for (int r = 0; r < 4; ++r) {
            int row_local = wm * RM + mt * 16 + quad * 4 + r;
            int gm = mtb * BMT + row_local;
            if (gm >= cnt) continue;
            int p = rowid[row_local];
            #pragma unroll
            for (int nt = 0; nt < NTt; ++nt) {
                int col = ntb * BNT + wn * RN + nt * 16 + lrow;
                float g = accg[mt][nt][r], u = accu[mt][nt][r];
                float h = (g / (1.f + __expf(-g))) * u;
                Hout[(size_t)p * ND + col] = (__bf16)h;
            }
        }
}

// ---------------- down projection, bf16 MFMA, small tiles for TLP ----------------
// Hin bf16 [rows, KD]; Wd fp32 [(E,) HD, KD]; out fp32 [NT, HD]
template<bool EXPERT, int KD, int BMT, int BNT>
__global__ void __launch_bounds__(256) down_mfma(
    const bf16_t* __restrict__ Hin, const float* __restrict__ Wd,
    float* __restrict__ out, const int* __restrict__ lists,
    const int* __restrict__ counts, const float* __restrict__ topkw)
{
    int e = 0, cnt = NT;
    const float* wd = Wd;
    if (EXPERT) {
        e = blockIdx.x; cnt = counts[e];
        wd = Wd + (size_t)e * HD * KD;
    }
    int mtb = blockIdx.y, ntb = blockIdx.z;
    if (mtb * BMT >= cnt) return;

    constexpr int RM = BMT / 2;
    constexpr int RN = BNT / 2;
    constexpr int MT = RM / 16;
    constexpr int NTt = RN / 16;
    constexpr int ARH = (BMT * BK) / (256 * 8);   // bf16x8/thread for A
    constexpr int BR = (BNT * BK) / (256 * 4);    // float4/thread for W

    __shared__ __align__(16) bf16_t As[BMT * LDA];
    __shared__ __align__(16) bf16_t Wsh[BNT * LDA];
    __shared__ int rowid[BMT];

    int tid = threadIdx.x;
    if (tid < BMT) {
        int gm = mtb * BMT + tid;
        int mm = gm < cnt ? gm : cnt - 1;
        rowid[tid] = EXPERT ? lists[e * NT + mm] : mm;
    }
    __syncthreads();

    int lane = tid & 63;
    int w = tid >> 6;
    int wm = w & 1, wn = w >> 1;
    int lrow = lane & 15, quad = lane >> 4;

    f32x4 acc[MT][NTt];
    #pragma unroll
    for (int i = 0; i < MT; ++i)
        #pragma unroll
        for (int j = 0; j < NTt; ++j) acc[i][j] = (f32x4){0,0,0,0};

    for (int k0 = 0; k0 < KD; k0 += BK) {
        #pragma unroll
        for (int r = 0; r < ARH; ++r) {
            int idx = r * 256 + tid;
            int row = idx >> 2, c = idx & 3;
            bf16x8 v = *(const bf16x8*)(Hin + (size_t)rowid[row] * KD + k0 + c * 8);
            *(bf16x8*)(As + row * LDA + c * 8) = v;
        }
        #pragma unroll
        for (int r = 0; r < BR; ++r) {
            int idx = r * 256 + tid;
            int n = idx >> 3, kq = idx & 7;
            size_t off = (size_t)(ntb * BNT + n) * KD + k0 + kq * 4;
            *(bf16x4*)(Wsh + n * LDA + kq * 4) = cvt4(*(const float4*)(wd + off));
        }
        __syncthreads();

        bf16x8 af[MT], bf[NTt];
        #pragma unroll
        for (int mt = 0; mt < MT; ++mt)
            af[mt] = *(const bf16x8*)(As + (wm * RM + mt * 16 + lrow) * LDA + quad * 8);
        #pragma unroll
        for (int nt = 0; nt < NTt; ++nt)
            bf[nt] = *(const bf16x8*)(Wsh + (wn * RN + nt * 16 + lrow) * LDA + quad * 8);
        #pragma unroll
        for (int mt = 0; mt < MT; ++mt)
            #pragma unroll
            for (int nt = 0; nt < NTt; ++nt)
                acc[mt][nt] = __builtin_amdgcn_mfma_f32_16x16x32_bf16(af[mt], bf[nt], acc[mt][nt], 0, 0, 0);
        __syncthreads();
    }

    #pragma unroll
    for (int mt = 0; mt < MT; ++mt)
        #pragma unroll
        for (int r = 0; r < 4; ++r) {
            int row_local = wm * RM + mt * 16 + quad * 4 + r;
            int gm = mtb * BMT + row_local;
            if (gm >= cnt) continue;
            int p = rowid[row_local];
            #pragma unroll
            for (int nt = 0; nt < NTt; ++nt) {
                int col = ntb * BNT + wn * RN + nt * 16 + lrow;
                float val = acc[mt][nt][r];
                if (EXPERT) {
                    float wgt = topkw[p];
                    atomicAdd(&out[(size_t)(p >> 2) * HD + col], wgt * val);
                } else {
                    out[(size_t)p * HD + col] = val;
                }
            }
        }
}

extern "C" void kernel_launch(void* const* d_in, const int* in_sizes, int n_in,
                              void* d_out, int out_size, void* d_ws, size_t ws_size,
                              hipStream_t stream) {
    const float* hs  = (const float*)d_in[0];
    const float* rw  = (const float*)d_in[1];
    const float* rb  = (const float*)d_in[2];
    const float* gw  = (const float*)d_in[3];
    const float* uw  = (const float*)d_in[4];
    const float* dw  = (const float*)d_in[5];
    const float* sgw = (const float*)d_in[6];
    const float* suw = (const float*)d_in[7];
    const float* sdw = (const float*)d_in[8];
    float* out = (float*)d_out;

    // workspace layout
    char* ws = (char*)d_ws;
    int*    counts = (int*)ws;                                  // 128 B
    float*  topkw  = (float*)(ws + 128);                        // 32 KB
    int*    lists  = (int*)(ws + 128 + 32768);                  // 256 KB
    float*  logits = (float*)(ws + 128 + 32768 + 262144);       // 256 KB
    bf16_t* hbuf   = (bf16_t*)(ws + 128 + 32768 + 262144 + 262144);  // 8.4 MB

    // router
    logits_kernel<<<NT / LTOK, 256, 0, stream>>>(hs, rw, logits, counts);
    topk_kernel<<<NT / 256, 256, 0, stream>>>(logits, rb, topkw, counts, lists);

    // shared expert: 64x32 tiles -> 1024 blocks each
    gateup_mfma<false, SHI, 64, 32><<<dim3(1, NT / 64, SHI / 32), 256, 0, stream>>>(
        hs, sgw, suw, hbuf, nullptr, nullptr);
    down_mfma<false, SHI, 64, 32><<<dim3(1, NT / 64, HD / 32), 256, 0, stream>>>(
        hbuf, sdw, out, nullptr, nullptr, nullptr);

    // routed experts: gateup 64x32 (~2100 active blocks), down 64x64 (~2080)
    gateup_mfma<true, ID, 64, 32><<<dim3(NE, NT / 64, ID / 32), 256, 0, stream>>>(
        hs, gw, uw, hbuf, lists, counts);
    down_mfma<true, ID, 64, 64><<<dim3(NE, NT / 64, HD / 64), 256, 0, stream>>>(
        hbuf, dw, out, lists, counts, topkw);
}

// Round 6
// 415.961 us; speedup vs baseline: 1.2361x; 1.2361x over previous
//
#include <hip/hip_runtime.h>
#include <hip/hip_bf16.h>
#include <math.h>

// Problem constants
#define HD 1024     // hidden H
#define ID 512      // moe intermediate I
#define NE 32       // n experts
#define NT 2048     // tokens T = B*S
#define NG 4        // n_group
#define SHI 1024    // shared intermediate I*N_SHARED
#define SCALE 2.5f

#define BK 32
#define LDAF 40     // fp32-path LDS row stride (fallback kernels)

typedef __bf16 bf16_t;
typedef __attribute__((ext_vector_type(8))) __bf16 bf16x8;
typedef __attribute__((ext_vector_type(4))) __bf16 bf16x4;
typedef __attribute__((ext_vector_type(4))) float f32x4;

__device__ inline void load_lds16(const void* g, void* l) {
    __builtin_amdgcn_global_load_lds(
        (const __attribute__((address_space(1))) void*)g,
        (__attribute__((address_space(3))) void*)l, 16, 0, 0);
}

// ---------------- fp32 -> bf16 stream convert ----------------
__global__ void __launch_bounds__(256) cvt_bf16_kernel(
    const float* __restrict__ in, bf16_t* __restrict__ out, int n8)
{
    int stride = gridDim.x * 256;
    for (int i = blockIdx.x * 256 + threadIdx.x; i < n8; i += stride) {
        const float4* p = (const float4*)(in + (size_t)i * 8);
        float4 a = p[0], b = p[1];
        bf16x8 v;
        v[0] = (__bf16)a.x; v[1] = (__bf16)a.y; v[2] = (__bf16)a.z; v[3] = (__bf16)a.w;
        v[4] = (__bf16)b.x; v[5] = (__bf16)b.y; v[6] = (__bf16)b.z; v[7] = (__bf16)b.w;
        *(bf16x8*)(out + (size_t)i * 8) = v;
    }
}

// ---------------- router stage 1: logits GEMM + zero counts ----------------
#define LTOK 8
#define LKC 64
__global__ void __launch_bounds__(256) logits_kernel(
    const float* __restrict__ hs, const float* __restrict__ rw,
    float* __restrict__ logits, int* __restrict__ counts)
{
    if (blockIdx.x == 0 && threadIdx.x < NE) counts[threadIdx.x] = 0;

    __shared__ float Xs[LTOK][68];
    __shared__ float Ws[NE][65];

    int tid = threadIdx.x;
    int t0 = blockIdx.x * LTOK;
    int tslot = tid >> 5, ecol = tid & 31;
    float acc = 0.f;

    for (int k0 = 0; k0 < HD; k0 += LKC) {
        if (tid < 128) {
            int row = tid >> 4, q = tid & 15;
            float4 v = *(const float4*)(hs + (size_t)(t0 + row) * HD + k0 + q * 4);
            *(float4*)(&Xs[row][q * 4]) = v;
        }
        #pragma unroll
        for (int i = 0; i < 8; ++i) {
            int idx = i * 256 + tid;
            int e = idx >> 6, kk = idx & 63;
            Ws[e][kk] = rw[(size_t)e * HD + k0 + kk];
        }
        __syncthreads();
        #pragma unroll 8
        for (int kk = 0; kk < LKC; ++kk)
            acc += Xs[tslot][kk] * Ws[ecol][kk];
        __syncthreads();
    }
    logits[(size_t)(t0 + tslot) * NE + ecol] = acc;
}

// ---------------- router stage 2: per-token top-k ----------------
__global__ void __launch_bounds__(256) topk_kernel(
    const float* __restrict__ logits, const float* __restrict__ rb,
    float* __restrict__ topkw, int* __restrict__ counts, int* __restrict__ lists)
{
    int t = blockIdx.x * 256 + threadIdx.x;
    if (t >= NT) return;

    float scores[NE], sfc[NE], tmp[NE];
    #pragma unroll
    for (int e = 0; e < NE; ++e) {
        float l = logits[(size_t)t * NE + e];
        float s = 1.f / (1.f + __expf(-l));
        scores[e] = s;
        sfc[e] = s + rb[e];
    }
    float gs[NG];
    #pragma unroll
    for (int g = 0; g < NG; ++g) {
        float m1 = -1e30f, m2 = -1e30f;
        #pragma unroll
        for (int j = 0; j < 8; ++j) {
            float v = sfc[g * 8 + j];
            if (v > m1) { m2 = m1; m1 = v; } else if (v > m2) m2 = v;
        }
        gs[g] = m1 + m2;
    }
    int g1 = 0;
    #pragma unroll
    for (int g = 1; g < NG; ++g) if (gs[g] > gs[g1]) g1 = g;
    int g2 = -1;
    #pragma unroll
    for (int g = 0; g < NG; ++g) {
        if (g == g1) continue;
        if (g2 < 0 || gs[g] > gs[g2]) g2 = g;
    }
    #pragma unroll
    for (int e = 0; e < NE; ++e) {
        int g = e >> 3;
        tmp[e] = (g == g1 || g == g2) ? sfc[e] : 0.0f;
    }
    int idx[4]; float wk[4]; float wsum = 0.f;
    #pragma unroll
    for (int k = 0; k < 4; ++k) {
        int best = 0; float bv = -1e30f;
        #pragma unroll
        for (int e = 0; e < NE; ++e) if (tmp[e] > bv) { bv = tmp[e]; best = e; }
        idx[k] = best; tmp[best] = -1e30f;
        wk[k] = scores[best]; wsum += wk[k];
    }
    float inv = SCALE / (wsum + 1e-20f);
    #pragma unroll
    for (int k = 0; k < 4; ++k) {
        int p = t * 4 + k;
        topkw[p] = wk[k] * inv;
        int e = idx[k];
        int pos = atomicAdd(&counts[e], 1);
        lists[e * NT + pos] = p;
    }
}

__device__ inline bf16x4 cvt4(float4 v) {
    bf16x4 r;
    r[0] = (__bf16)v.x; r[1] = (__bf16)v.y; r[2] = (__bf16)v.z; r[3] = (__bf16)v.w;
    return r;
}

// ================= PRIMARY PATH: all-bf16, global_load_lds staging =================
// m97-style: 128x64 tile, BK=32, LDA=BK (unpadded, contiguous for global_load_lds),
// 2-barrier K-loop, 4 waves in 2x2.

// fused gate/up + SwiGLU
template<bool EXPERT, int ND>
__global__ void __launch_bounds__(256) gateup_bf16(
    const bf16_t* __restrict__ X, const bf16_t* __restrict__ Wg,
    const bf16_t* __restrict__ Wu, bf16_t* __restrict__ Hout,
    const int* __restrict__ lists, const int* __restrict__ counts)
{
    int e = 0, cnt = NT;
    const bf16_t* wg = Wg; const bf16_t* wu = Wu;
    if (EXPERT) {
        e = blockIdx.x; cnt = counts[e];
        wg = Wg + (size_t)e * ND * HD;
        wu = Wu + (size_t)e * ND * HD;
    }
    int mtb = blockIdx.y, ntb = blockIdx.z;
    if (mtb * 128 >= cnt) return;

    __shared__ __align__(16) bf16_t As[128 * 32];
    __shared__ __align__(16) bf16_t Bgs[64 * 32];
    __shared__ __align__(16) bf16_t Bus[64 * 32];
    __shared__ int rowid[128];

    int tid = threadIdx.x;
    if (tid < 128) {
        int gm = mtb * 128 + tid;
        int mm = gm < cnt ? gm : cnt - 1;
        rowid[tid] = EXPERT ? lists[e * NT + mm] : mm;
    }
    __syncthreads();

    int lane = tid & 63, w = tid >> 6;
    int wm = w & 1, wn = w >> 1;
    int lrow = lane & 15, quad = lane >> 4;

    // staging addresses: each instr stages 16 rows x 32 bf16 (64B rows, 4 chunks of 16B)
    int sr = lane >> 2, sc = lane & 3;
    int arow0 = w * 32 + sr;
    int arow1 = w * 32 + 16 + sr;
    int tokA0 = EXPERT ? (rowid[arow0] >> 2) : rowid[arow0];
    int tokA1 = EXPERT ? (rowid[arow1] >> 2) : rowid[arow1];
    const bf16_t* ga0 = X + (size_t)tokA0 * HD + sc * 8;
    const bf16_t* ga1 = X + (size_t)tokA1 * HD + sc * 8;
    bf16_t* la0 = As + (w * 32) * 32 + lane * 8;
    bf16_t* la1 = As + (w * 32 + 16) * 32 + lane * 8;

    int brow = w * 16 + sr;
    const bf16_t* gbg = wg + (size_t)(ntb * 64 + brow) * HD + sc * 8;
    const bf16_t* gbu = wu + (size_t)(ntb * 64 + brow) * HD + sc * 8;
    bf16_t* lbg = Bgs + (w * 16) * 32 + lane * 8;
    bf16_t* lbu = Bus + (w * 16) * 32 + lane * 8;

    f32x4 accg[4][2], accu[4][2];
    #pragma unroll
    for (int i = 0; i < 4; ++i)
        #pragma unroll
        for (int j = 0; j < 2; ++j) { accg[i][j] = (f32x4){0,0,0,0}; accu[i][j] = (f32x4){0,0,0,0}; }

    for (int k0 = 0; k0 < HD; k0 += BK) {
        load_lds16(ga0 + k0, la0);
        load_lds16(ga1 + k0, la1);
        load_lds16(gbg + k0, lbg);
        load_lds16(gbu + k0, lbu);
        __syncthreads();   // drains vmcnt, publishes LDS

        bf16x8 af[4], bg[2], bu[2];
        #pragma unroll
        for (int mt = 0; mt < 4; ++mt)
            af[mt] = *(const bf16x8*)(As + (wm * 64 + mt * 16 + lrow) * 32 + quad * 8);
        #pragma unroll
        for (int nt = 0; nt < 2; ++nt) {
            bg[nt] = *(const bf16x8*)(Bgs + (wn * 32 + nt * 16 + lrow) * 32 + quad * 8);
            bu[nt] = *(const bf16x8*)(Bus + (wn * 32 + nt * 16 + lrow) * 32 + quad * 8);
        }
        #pragma unroll
        for (int mt = 0; mt < 4; ++mt)
            #pragma unroll
            for (int nt = 0; nt < 2; ++nt) {
                accg[mt][nt] = __builtin_amdgcn_mfma_f32_16x16x32_bf16(af[mt], bg[nt], accg[mt][nt], 0, 0, 0);
                accu[mt][nt] = __builtin_amdgcn_mfma_f32_16x16x32_bf16(af[mt], bu[nt], accu[mt][nt], 0, 0, 0);
            }
        __syncthreads();
    }

    #pragma unroll
    for (int mt = 0; mt < 4; ++mt)
        #pragma unroll
        for (int r = 0; r < 4; ++r) {
            int row_local = wm * 64 + mt * 16 + quad * 4 + r;
            int gm = mtb * 128 + row_local;
            if (gm >= cnt) continue;
            int p = rowid[row_local];
            #pragma unroll
            for (int nt = 0; nt < 2; ++nt) {
                int col = ntb * 64 + wn * 32 + nt * 16 + lrow;
                float g = accg[mt][nt][r], u = accu[mt][nt][r];
                float h = (g / (1.f + __expf(-g))) * u;
                Hout[(size_t)p * ND + col] = (__bf16)h;
            }
        }
}

// down projection
template<bool EXPERT, int KD>
__global__ void __launch_bounds__(256) down_bf16(
    const bf16_t* __restrict__ Hin, const bf16_t* __restrict__ Wd,
    float* __restrict__ out, const int* __restrict__ lists,
    const int* __restrict__ counts, const float* __restrict__ topkw)
{
    int e = 0, cnt = NT;
    const bf16_t* wd = Wd;
    if (EXPERT) {
        e = blockIdx.x; cnt = counts[e];
        wd = Wd + (size_t)e * HD * KD;
    }
    int mtb = blockIdx.y, ntb = blockIdx.z;
    if (mtb * 128 >= cnt) return;

    __shared__ __align__(16) bf16_t As[128 * 32];
    __shared__ __align__(16) bf16_t Bs[64 * 32];
    __shared__ int rowid[128];

    int tid = threadIdx.x;
    if (tid < 128) {
        int gm = mtb * 128 + tid;
        int mm = gm < cnt ? gm : cnt - 1;
        rowid[tid] = EXPERT ? lists[e * NT + mm] : mm;
    }
    __syncthreads();

    int lane = tid & 63, w = tid >> 6;
    int wm = w & 1, wn = w >> 1;
    int lrow = lane & 15, quad = lane >> 4;

    int sr = lane >> 2, sc = lane & 3;
    int arow0 = w * 32 + sr;
    int arow1 = w * 32 + 16 + sr;
    const bf16_t* ga0 = Hin + (size_t)rowid[arow0] * KD + sc * 8;
    const bf16_t* ga1 = Hin + (size_t)rowid[arow1] * KD + sc * 8;
    bf16_t* la0 = As + (w * 32) * 32 + lane * 8;
    bf16_t* la1 = As + (w * 32 + 16) * 32 + lane * 8;

    int brow = w * 16 + sr;
    const bf16_t* gb = wd + (size_t)(ntb * 64 + brow) * KD + sc * 8;
    bf16_t* lb = Bs + (w * 16) * 32 + lane * 8;

    f32x4 acc[4][2];
    #pragma unroll
    for (int i = 0; i < 4; ++i)
        #pragma unroll
        for (int j = 0; j < 2; ++j) acc[i][j] = (f32x4){0,0,0,0};

    for (int k0 = 0; k0 < KD; k0 += BK) {
        load_lds16(ga0 + k0, la0);
        load_lds16(ga1 + k0, la1);
        load_lds16(gb + k0, lb);
        __syncthreads();

        bf16x8 af[4], bf[2];
        #pragma unroll
        for (int mt = 0; mt < 4; ++mt)
            af[mt] = *(const bf16x8*)(As + (wm * 64 + mt * 16 + lrow) * 32 + quad * 8);
        #pragma unroll
        for (int nt = 0; nt < 2; ++nt)
            bf[nt] = *(const bf16x8*)(Bs + (wn * 32 + nt * 16 + lrow) * 32 + quad * 8);
        #pragma unroll
        for (int mt = 0; mt < 4; ++mt)
            #pragma unroll
            for (int nt = 0; nt < 2; ++nt)
                acc[mt][nt] = __builtin_amdgcn_mfma_f32_16x16x32_bf16(af[mt], bf[nt], acc[mt][nt], 0, 0, 0);
        __syncthreads();
    }

    #pragma unroll
    for (int mt = 0; mt < 4; ++mt)
        #pragma unroll
        for (int r = 0; r < 4; ++r) {
            int row_local = wm * 64 + mt * 16 + quad * 4 + r;
            int gm = mtb * 128 + row_local;
            if (gm >= cnt) continue;
            int p = rowid[row_local];
            #pragma unroll
            for (int nt = 0; nt < 2; ++nt) {
                int col = ntb * 64 + wn * 32 + nt * 16 + lrow;
                float val = acc[mt][nt][r];
                if (EXPERT) {
                    float wgt = topkw[p];
                    atomicAdd(&out[(size_t)(p >> 2) * HD + col], wgt * val);
                } else {
                    out[(size_t)p * HD + col] = val;
                }
            }
        }
}

// ================= FALLBACK PATH (R3): fp32 inputs, sync staging =================
template<bool EXPERT, int ND>
__global__ void __launch_bounds__(256) gateup_f32(
    const float* __restrict__ X, const float* __restrict__ Wg,
    const float* __restrict__ Wu, bf16_t* __restrict__ Hout,
    const int* __restrict__ lists, const int* __restrict__ counts)
{
    int e = 0, cnt = NT;
    const float* wg = Wg; const float* wu = Wu;
    if (EXPERT) {
        e = blockIdx.x; cnt = counts[e];
        wg = Wg + (size_t)e * ND * HD;
        wu = Wu + (size_t)e * ND * HD;
    }
    int mtb = blockIdx.y, ntb = blockIdx.z;
    if (mtb * 128 >= cnt) return;

    __shared__ __align__(16) bf16_t As[128 * LDAF];
    __shared__ __align__(16) bf16_t Bgs[64 * LDAF];
    __shared__ __align__(16) bf16_t Bus[64 * LDAF];
    __shared__ int rowid[128];

    int tid = threadIdx.x;
    if (tid < 128) {
        int gm = mtb * 128 + tid;
        int mm = gm < cnt ? gm : cnt - 1;
        rowid[tid] = EXPERT ? lists[e * NT + mm] : mm;
    }
    __syncthreads();

    int lane = tid & 63, w = tid >> 6;
    int wm = w & 1, wn = w >> 1;
    int lrow = lane & 15, quad = lane >> 4;

    f32x4 accg[4][2], accu[4][2];
    #pragma unroll
    for (int i = 0; i < 4; ++i)
        #pragma unroll
        for (int j = 0; j < 2; ++j) { accg[i][j] = (f32x4){0,0,0,0}; accu[i][j] = (f32x4){0,0,0,0}; }

    for (int k0 = 0; k0 < HD; k0 += BK) {
        #pragma unroll
        for (int r = 0; r < 4; ++r) {
            int idx = r * 256 + tid;
            int row = idx >> 3, kq = idx & 7;
            int tok = EXPERT ? (rowid[row] >> 2) : rowid[row];
            float4 v = *(const float4*)(X + (size_t)tok * HD + k0 + kq * 4);
            *(bf16x4*)(As + row * LDAF + kq * 4) = cvt4(v);
        }
        #pragma unroll
        for (int r = 0; r < 2; ++r) {
            int idx = r * 256 + tid;
            int n = idx >> 3, kq = idx & 7;
            size_t off = (size_t)(ntb * 64 + n) * HD + k0 + kq * 4;
            *(bf16x4*)(Bgs + n * LDAF + kq * 4) = cvt4(*(const float4*)(wg + off));
            *(bf16x4*)(Bus + n * LDAF + kq * 4) = cvt4(*(const float4*)(wu + off));
        }
        __syncthreads();

        bf16x8 af[4], bg[2], bu[2];
        #pragma unroll
        for (int mt = 0; mt < 4; ++mt)
            af[mt] = *(const bf16x8*)(As + (wm * 64 + mt * 16 + lrow) * LDAF + quad * 8);
        #pragma unroll
        for (int nt = 0; nt < 2; ++nt) {
            bg[nt] = *(const bf16x8*)(Bgs + (wn * 32 + nt * 16 + lrow) * LDAF + quad * 8);
            bu[nt] = *(const bf16x8*)(Bus + (wn * 32 + nt * 16 + lrow) * LDAF + quad * 8);
        }
        #pragma unroll
        for (int mt = 0; mt < 4; ++mt)
            #pragma unroll
            for (int nt = 0; nt < 2; ++nt) {
                accg[mt][nt] = __builtin_amdgcn_mfma_f32_16x16x32_bf16(af[mt], bg[nt], accg[mt][nt], 0, 0, 0);
                accu[mt][nt] = __builtin_amdgcn_mfma_f32_16x16x32_bf16(af[mt], bu[nt], accu[mt][nt], 0, 0, 0);
            }
        __syncthreads();
    }

    #pragma unroll
    for (int mt = 0; mt < 4; ++mt)
        #pragma unroll
        for (int r = 0; r < 4; ++r) {
            int row_local = wm * 64 + mt * 16 + quad * 4 + r;
            int gm = mtb * 128 + row_local;
            if (gm >= cnt) continue;
            int p = rowid[row_local];
            #pragma unroll
            for (int nt = 0; nt < 2; ++nt) {
                int col = ntb * 64 + wn * 32 + nt * 16 + lrow;
                float g = accg[mt][nt][r], u = accu[mt][nt][r];
                float h = (g / (1.f + __expf(-g))) * u;
                Hout[(size_t)p * ND + col] = (__bf16)h;
            }
        }
}

template<bool EXPERT, int KD>
__global__ void __launch_bounds__(256) down_f32(
    const bf16_t* __restrict__ Hin, const float* __restrict__ Wd,
    float* __restrict__ out, const int* __restrict__ lists,
    const int* __restrict__ counts, const float* __restrict__ topkw)
{
    int e = 0, cnt = NT;
    const float* wd = Wd;
    if (EXPERT) {
        e = blockIdx.x; cnt = counts[e];
        wd = Wd + (size_t)e * HD * KD;
    }
    int mtb = blockIdx.y, ntb = blockIdx.z;
    if (mtb * 128 >= cnt) return;

    __shared__ __align__(16) bf16_t As[128 * LDAF];
    __shared__ __align__(16) bf16_t Bs[64 * LDAF];
    __shared__ int rowid[128];

    int tid = threadIdx.x;
    if (tid < 128) {
        int gm = mtb * 128 + tid;
        int mm = gm < cnt ? gm : cnt - 1;
        rowid[tid] = EXPERT ? lists[e * NT + mm] : mm;
    }
    __syncthreads();

    int lane = tid & 63, w = tid >> 6;
    int wm = w & 1, wn = w >> 1;
    int lrow = lane & 15, quad = lane >> 4;

    f32x4 acc[4][2];
    #pragma unroll
    for (int i = 0; i < 4; ++i)
        #pragma unroll
        for (int j = 0; j < 2; ++j) acc[i][j] = (f32x4){0,0,0,0};

    for (int k0 = 0; k0 < KD; k0 += BK) {
        #pragma unroll
        for (int r = 0; r < 2; ++r) {
            int idx = r * 256 + tid;
            int row = idx >> 2, c = idx & 3;
            bf16x8 v = *(const bf16x8*)(Hin + (size_t)rowid[row] * KD + k0 + c * 8);
            *(bf16x8*)(As + row * LDAF + c * 8) = v;
        }
        #pragma unroll
        for (int r = 0; r < 2; ++r) {
            int idx = r * 256 + tid;
            int n = idx >> 3, kq = idx & 7;
            size_t off = (size_t)(ntb * 64 + n) * KD + k0 + kq * 4;
            *(bf16x4*)(Bs + n * LDAF + kq * 4) = cvt4(*(const float4*)(wd + off));
        }
        __syncthreads();

        bf16x8 af[4], bf[2];
        #pragma unroll
        for (int mt = 0; mt < 4; ++mt)
            af[mt] = *(const bf16x8*)(As + (wm * 64 + mt * 16 + lrow) * LDAF + quad * 8);
        #pragma unroll
        for (int nt = 0; nt < 2; ++nt)
            bf[nt] = *(const bf16x8*)(Bs + (wn * 32 + nt * 16 + lrow) * LDAF + quad * 8);
        #pragma unroll
        for (int mt = 0; mt < 4; ++mt)
            #pragma unroll
            for (int nt = 0; nt < 2; ++nt)
                acc[mt][nt] = __builtin_amdgcn_mfma_f32_16x16x32_bf16(af[mt], bf[nt], acc[mt][nt], 0, 0, 0);
        __syncthreads();
    }

    #pragma unroll
    for (int mt = 0; mt < 4; ++mt)
        #pragma unroll
        for (int r = 0; r < 4; ++r) {
            int row_local = wm * 64 + mt * 16 + quad * 4 + r;
            int gm = mtb * 128 + row_local;
            if (gm >= cnt) continue;
            int p = rowid[row_local];
            #pragma unroll
            for (int nt = 0; nt < 2; ++nt) {
                int col = ntb * 64 + wn * 32 + nt * 16 + lrow;
                float val = acc[mt][nt][r];
                if (EXPERT) {
                    float wgt = topkw[p];
                    atomicAdd(&out[(size_t)(p >> 2) * HD + col], wgt * val);
                } else {
                    out[(size_t)p * HD + col] = val;
                }
            }
        }
}

extern "C" void kernel_launch(void* const* d_in, const int* in_sizes, int n_in,
                              void* d_out, int out_size, void* d_ws, size_t ws_size,
                              hipStream_t stream) {
    const float* hs  = (const float*)d_in[0];
    const float* rw  = (const float*)d_in[1];
    const float* rb  = (const float*)d_in[2];
    const float* gw  = (const float*)d_in[3];
    const float* uw  = (const float*)d_in[4];
    const float* dw  = (const float*)d_in[5];
    const float* sgw = (const float*)d_in[6];
    const float* suw = (const float*)d_in[7];
    const float* sdw = (const float*)d_in[8];
    float* out = (float*)d_out;

    // workspace layout
    char* ws = (char*)d_ws;
    size_t off = 0;
    int*    counts = (int*)(ws + off);   off += 128;
    float*  topkw  = (float*)(ws + off); off += (size_t)NT * 4 * 4;        // 32 KB
    int*    lists  = (int*)(ws + off);   off += (size_t)NE * NT * 4;       // 256 KB
    float*  logits = (float*)(ws + off); off += (size_t)NT * NE * 4;       // 256 KB
    bf16_t* hbuf   = (bf16_t*)(ws + off); off += (size_t)NT * 4 * ID * 2;  // 8.39 MB (>= 2048*1024*2 for shared)
    size_t base_small = off;
    bf16_t* hsb  = (bf16_t*)(ws + off); off += (size_t)NT * HD * 2;
    bf16_t* gwb  = (bf16_t*)(ws + off); off += (size_t)NE * ID * HD * 2;
    bf16_t* uwb  = (bf16_t*)(ws + off); off += (size_t)NE * ID * HD * 2;
    bf16_t* dwb  = (bf16_t*)(ws + off); off += (size_t)NE * HD * ID * 2;
    bf16_t* sgwb = (bf16_t*)(ws + off); off += (size_t)SHI * HD * 2;
    bf16_t* suwb = (bf16_t*)(ws + off); off += (size_t)SHI * HD * 2;
    bf16_t* sdwb = (bf16_t*)(ws + off); off += (size_t)HD * SHI * 2;
    bool big = (ws_size >= off);
    (void)base_small;

    // router (fp32, bit-identical routing decisions)
    logits_kernel<<<NT / LTOK, 256, 0, stream>>>(hs, rw, logits, counts);
    topk_kernel<<<NT / 256, 256, 0, stream>>>(logits, rb, topkw, counts, lists);

    if (big) {
        // convert inputs/weights to bf16 (streaming, HBM-bound)
        cvt_bf16_kernel<<<512, 256, 0, stream>>>(hs, hsb, NT * HD / 8);
        cvt_bf16_kernel<<<2048, 256, 0, stream>>>(gw, gwb, NE * ID * HD / 8);
        cvt_bf16_kernel<<<2048, 256, 0, stream>>>(uw, uwb, NE * ID * HD / 8);
        cvt_bf16_kernel<<<2048, 256, 0, stream>>>(dw, dwb, NE * HD * ID / 8);
        cvt_bf16_kernel<<<512, 256, 0, stream>>>(sgw, sgwb, SHI * HD / 8);
        cvt_bf16_kernel<<<512, 256, 0, stream>>>(suw, suwb, SHI * HD / 8);
        cvt_bf16_kernel<<<512, 256, 0, stream>>>(sdw, sdwb, HD * SHI / 8);

        // shared expert
        gateup_bf16<false, SHI><<<dim3(1, NT / 128, SHI / 64), 256, 0, stream>>>(
            hsb, sgwb, suwb, hbuf, nullptr, nullptr);
        down_bf16<false, SHI><<<dim3(1, NT / 128, HD / 64), 256, 0, stream>>>(
            hbuf, sdwb, out, nullptr, nullptr, nullptr);

        // routed experts
        gateup_bf16<true, ID><<<dim3(NE, NT / 128, ID / 64), 256, 0, stream>>>(
            hsb, gwb, uwb, hbuf, lists, counts);
        down_bf16<true, ID><<<dim3(NE, NT / 128, HD / 64), 256, 0, stream>>>(
            hbuf, dwb, out, lists, counts, topkw);
    } else {
        // fallback: fp32 staging (R3 structure)
        gateup_f32<false, SHI><<<dim3(1, NT / 128, SHI / 64), 256, 0, stream>>>(
            hs, sgw, suw, hbuf, nullptr, nullptr);
        down_f32<false, SHI><<<dim3(1, NT / 128, HD / 64), 256, 0, stream>>>(
            hbuf, sdw, out, nullptr, nullptr, nullptr);
        gateup_f32<true, ID><<<dim3(NE, NT / 128, ID / 64), 256, 0, stream>>>(
            hs, gw, uw, hbuf, lists, counts);
        down_f32<true, ID><<<dim3(NE, NT / 128, HD / 64), 256, 0, stream>>>(
            hbuf, dw, out, lists, counts, topkw);
    }
}